// Round 2
// baseline (62.417 us; speedup 1.0000x reference)
//
#include <hip/hip_runtime.h>

// GCLSTM (K=1 Cheb, H0=C0=0) fused kernel for MI355X — v2.
// Math: i=sig(x@Wi+bi'), t=tanh(x@Wc+bc'), C=i*t, o=sig(x@Wo+bo'+wco*C),
//       out = (o*tanh(C)) @ fcW + fcb.  edge_index/batch/Wg_*/W_f unused.
// v2: 64 rows/wave, GEMM2 interleaved per 32-hid block (tiny dbuf LDS,
//     no barriers), bias folded into acc init, launch_bounds(128,2).

typedef __attribute__((ext_vector_type(8))) short short8;
typedef __attribute__((ext_vector_type(4))) short short4_t;
typedef __attribute__((ext_vector_type(4))) float f32x4;

#define N_ROWS 200000
#define IN_DIM 64
#define HID 128
#define OUT_DIM 64

// ws layout (bytes)
#define WFRAG_ELEMS (24 * 2 * 64 * 8)   // 24576 bf16
#define FCFRAG_OFF  49152               // WFRAG_ELEMS*2
#define FCFRAG_ELEMS (4 * 4 * 64 * 8)   // 8192 bf16
#define BIAS_OFF    65536               // floats: bi[128],bc[128],bo[128],wco[128],fcb[64]

__device__ __forceinline__ short f2bf(float f) {
  unsigned u = __float_as_uint(f);
  u += 0x7FFFu + ((u >> 16) & 1u);   // RNE
  return (short)(u >> 16);
}
__device__ __forceinline__ float fexp2(float z) { return __builtin_amdgcn_exp2f(z); }
__device__ __forceinline__ float frcp(float z)  { return __builtin_amdgcn_rcpf(z); }
__device__ __forceinline__ float fsigmoid(float z) {
  return frcp(1.0f + fexp2(-1.44269504f * z));
}
__device__ __forceinline__ float ftanh(float z) {
  return 1.0f - 2.0f * frcp(1.0f + fexp2(2.88539008f * z));
}

// ---- repack: weights -> bf16 MFMA A-fragments, biases -> combined fp32 ----
__global__ void repack_kernel(const float* __restrict__ W_i, const float* __restrict__ W_c,
                              const float* __restrict__ W_o, const float* __restrict__ fc_W,
                              const float* __restrict__ bg_i, const float* __restrict__ bg_c,
                              const float* __restrict__ bg_o,
                              const float* __restrict__ b_i, const float* __restrict__ b_c,
                              const float* __restrict__ b_o, const float* __restrict__ wc_o,
                              const float* __restrict__ fc_b,
                              short* __restrict__ wfrag, short* __restrict__ fcfrag,
                              float* __restrict__ bias) {
  int tid = blockIdx.x * blockDim.x + threadIdx.x;
  const int total1 = WFRAG_ELEMS;
  const int total2 = FCFRAG_ELEMS;
  for (int e = tid; e < total1 + total2 + HID + OUT_DIM; e += gridDim.x * blockDim.x) {
    if (e < total1) {
      // A-frag of first GEMM: A = Wcat^T (384x64). tile t: rows 16t+cidx; k=32s+8q+j
      int j = e & 7, lane = (e >> 3) & 63, s = (e >> 9) & 1, t = e >> 10;
      int q = lane >> 4, cidx = lane & 15;
      int gate = t >> 3;                       // 0:W_i 1:W_c 2:W_o
      int h = (t & 7) * 16 + cidx;
      int feat = 32 * s + 8 * q + j;
      const float* W = (gate == 0) ? W_i : ((gate == 1) ? W_c : W_o);
      wfrag[e] = f2bf(W[feat * HID + h]);
    } else if (e < total1 + total2) {
      // A-frag of second GEMM: A = fc_W^T (64x128). tile t: rows 16t+cidx; k=32s+8q+j
      int e2 = e - total1;
      int j = e2 & 7, lane = (e2 >> 3) & 63, s = (e2 >> 9) & 3, t = e2 >> 11;
      int q = lane >> 4, cidx = lane & 15;
      int od = 16 * t + cidx;
      int hid = 32 * s + 8 * q + j;
      fcfrag[e2] = f2bf(fc_W[hid * OUT_DIM + od]);
    } else if (e < total1 + total2 + HID) {
      int h = e - total1 - total2;
      bias[h]           = bg_i[h] + b_i[h];
      bias[HID + h]     = bg_c[h] + b_c[h];
      bias[2 * HID + h] = bg_o[h] + b_o[h];
      bias[3 * HID + h] = wc_o[h];
    } else {
      int h2 = e - total1 - total2 - HID;
      bias[4 * HID + h2] = fc_b[h2];
    }
  }
}

// ---- fused main kernel: 2 waves/WG, each wave owns 64 rows, no barriers ----
__global__ __launch_bounds__(128, 2) void gclstm_fused(
    const float* __restrict__ x, const short* __restrict__ wfrag,
    const short* __restrict__ fcfrag, const float* __restrict__ bias,
    float* __restrict__ out) {
  // 2 waves × 2 buffers × 64 rows × 32 hid bf16 = 16 KB, wave-private slices
  __shared__ short Hlds[2 * 2 * 64 * 32];
  const int lane = threadIdx.x & 63;
  const int wslot = threadIdx.x >> 6;
  const int wid = blockIdx.x * 2 + wslot;
  const int row0 = wid * 64;
  if (row0 >= N_ROWS) return;            // N_ROWS % 64 == 0, full tiles only
  const int q = lane >> 4, cidx = lane & 15;
  short* hb0 = Hlds + wslot * (2 * 64 * 32);

  // x B-fragments: B = x^T; lane supplies col (row row0+16m+cidx), k=32sk+8q+j
  short8 bx[4][2];
#pragma unroll
  for (int m = 0; m < 4; ++m) {
    const float* xr = x + (size_t)(row0 + 16 * m + cidx) * IN_DIM + 8 * q;
#pragma unroll
    for (int sk = 0; sk < 2; ++sk) {
      f32x4 f0 = *(const f32x4*)(xr + 32 * sk);
      f32x4 f1 = *(const f32x4*)(xr + 32 * sk + 4);
      short8 v;
      v[0] = f2bf(f0[0]); v[1] = f2bf(f0[1]); v[2] = f2bf(f0[2]); v[3] = f2bf(f0[3]);
      v[4] = f2bf(f1[0]); v[5] = f2bf(f1[1]); v[6] = f2bf(f1[2]); v[7] = f2bf(f1[3]);
      bx[m][sk] = v;
    }
  }

  const float* Bi  = bias;
  const float* Bc  = bias + HID;
  const float* Bo  = bias + 2 * HID;
  const float* Wco = bias + 3 * HID;
  const float* Fcb = bias + 4 * HID;

  // oacc init = fc bias (folded): lane holds out^T[od=16t+4q+r][xrow=16m+cidx]
  f32x4 oacc[4][4];
#pragma unroll
  for (int t = 0; t < 4; ++t) {
    f32x4 fb = *(const f32x4*)(Fcb + 16 * t + 4 * q);
#pragma unroll
    for (int m = 0; m < 4; ++m) oacc[t][m] = fb;
  }

#pragma unroll
  for (int s = 0; s < 4; ++s) {          // 32-hid block = GEMM2 k-step
    short* hb = hb0 + (s & 1) * (64 * 32);
#pragma unroll
    for (int gg = 0; gg < 2; ++gg) {     // two 16-h tiles within the block
      const int g = 2 * s + gg;
      const int h0 = g * 16 + 4 * q;
      // acc init = gate bias (folded)
      f32x4 vbi = *(const f32x4*)(Bi + h0);
      f32x4 vbc = *(const f32x4*)(Bc + h0);
      f32x4 vbo = *(const f32x4*)(Bo + h0);
      f32x4 vwc = *(const f32x4*)(Wco + h0);
      f32x4 acc[3][4];
#pragma unroll
      for (int m = 0; m < 4; ++m) { acc[0][m] = vbi; acc[1][m] = vbc; acc[2][m] = vbo; }
#pragma unroll
      for (int sk = 0; sk < 2; ++sk) {
        short8 ai = *(const short8*)(wfrag + (((g     ) * 2 + sk) * 64 + lane) * 8);
        short8 ac = *(const short8*)(wfrag + (((g +  8) * 2 + sk) * 64 + lane) * 8);
        short8 ao = *(const short8*)(wfrag + (((g + 16) * 2 + sk) * 64 + lane) * 8);
#pragma unroll
        for (int m = 0; m < 4; ++m) {
          acc[0][m] = __builtin_amdgcn_mfma_f32_16x16x32_bf16(ai, bx[m][sk], acc[0][m], 0, 0, 0);
          acc[1][m] = __builtin_amdgcn_mfma_f32_16x16x32_bf16(ac, bx[m][sk], acc[1][m], 0, 0, 0);
          acc[2][m] = __builtin_amdgcn_mfma_f32_16x16x32_bf16(ao, bx[m][sk], acc[2][m], 0, 0, 0);
        }
      }
      // gates; write H chunk (local hid 16gg+4q..+3) to LDS, XOR-swizzled
#pragma unroll
      for (int m = 0; m < 4; ++m) {
        short4_t hw;
#pragma unroll
        for (int r = 0; r < 4; ++r) {
          float gi = fsigmoid(acc[0][m][r]);
          float gt = ftanh(acc[1][m][r]);
          float C  = gi * gt;
          float go = fsigmoid(acc[2][m][r] + vwc[r] * C);
          hw[r] = f2bf(go * ftanh(C));
        }
        const int xrow = 16 * m + cidx;
        const int l0 = (16 * gg + 4 * q) ^ ((xrow & 3) << 3);
        *(short4_t*)(hb + xrow * 32 + l0) = hw;    // ds_write_b64
      }
    }
    // GEMM2 partial accumulate for this 32-hid block
    short8 bh[4];
#pragma unroll
    for (int m = 0; m < 4; ++m) {
      const int xrow = 16 * m + cidx;
      const int l0 = (8 * q) ^ ((xrow & 3) << 3);
      bh[m] = *(const short8*)(hb + xrow * 32 + l0);   // ds_read_b128
    }
#pragma unroll
    for (int t = 0; t < 4; ++t) {
      short8 af = *(const short8*)(fcfrag + ((t * 4 + s) * 64 + lane) * 8);
#pragma unroll
      for (int m = 0; m < 4; ++m)
        oacc[t][m] = __builtin_amdgcn_mfma_f32_16x16x32_bf16(af, bh[m], oacc[t][m], 0, 0, 0);
    }
  }

  // epilogue: coalesced float4 stores (fc bias already folded)
#pragma unroll
  for (int t = 0; t < 4; ++t) {
    const int od0 = 16 * t + 4 * q;
#pragma unroll
    for (int m = 0; m < 4; ++m) {
      *(f32x4*)(out + (size_t)(row0 + 16 * m + cidx) * OUT_DIM + od0) = oacc[t][m];
    }
  }
}

extern "C" void kernel_launch(void* const* d_in, const int* in_sizes, int n_in,
                              void* d_out, int out_size, void* d_ws, size_t ws_size,
                              hipStream_t stream) {
  (void)in_sizes; (void)n_in; (void)out_size; (void)ws_size;
  const float* x    = (const float*)d_in[0];
  const float* W_i  = (const float*)d_in[3];
  const float* W_c  = (const float*)d_in[5];
  const float* W_o  = (const float*)d_in[6];
  const float* bg_i = (const float*)d_in[11];
  const float* bg_c = (const float*)d_in[13];
  const float* bg_o = (const float*)d_in[14];
  const float* wc_o = (const float*)d_in[17];
  const float* b_i  = (const float*)d_in[18];
  const float* b_c  = (const float*)d_in[20];
  const float* b_o  = (const float*)d_in[21];
  const float* fc_W = (const float*)d_in[22];
  const float* fc_b = (const float*)d_in[23];

  short* wfrag  = (short*)d_ws;
  short* fcfrag = (short*)((char*)d_ws + FCFRAG_OFF);
  float* bias   = (float*)((char*)d_ws + BIAS_OFF);

  repack_kernel<<<dim3(64), dim3(256), 0, stream>>>(
      W_i, W_c, W_o, fc_W, bg_i, bg_c, bg_o, b_i, b_c, b_o, wc_o, fc_b,
      wfrag, fcfrag, bias);

  const int nwaves = N_ROWS / 64;           // 3125
  const int nwg = (nwaves + 1) / 2;         // 1563
  gclstm_fused<<<dim3(nwg), dim3(128), 0, stream>>>(
      x, wfrag, fcfrag, bias, (float*)d_out);
}

// Round 4
// 53.659 us; speedup vs baseline: 1.1632x; 1.1632x over previous
//
#include <hip/hip_runtime.h>

// GCLSTM (K=1 Cheb, H0=C0=0) fused kernel for MI355X — v4.
// Math: i=sig(x@Wi+bi'), t=tanh(x@Wc+bc'), C=i*t, o=sig(x@Wo+bo'+wco*C),
//       out = (o*tanh(C)) @ fcW + fcb.  edge_index/batch/Wg_*/W_f unused.
// v4: zero-LDS, zero-shuffle. The hid dimension is internally permuted
//     (h = 32s + 2gg + 8q + 4(r>>1) + (r&1)) so that each lane's GEMM1
//     gate outputs ARE its GEMM2 B-fragment. Weights/biases repacked to
//     match; fc_W fragment order is standard so output is exact.

typedef __attribute__((ext_vector_type(8))) short short8;
typedef __attribute__((ext_vector_type(4))) float f32x4;

#define N_ROWS 200000
#define IN_DIM 64
#define HID 128
#define OUT_DIM 64

// ws layout (bytes)
#define WFRAG_ELEMS (24 * 2 * 64 * 8)   // 24576 bf16
#define FCFRAG_OFF  49152               // WFRAG_ELEMS*2
#define FCFRAG_ELEMS (4 * 4 * 64 * 8)   // 8192 bf16
#define BIAS_OFF    65536               // floats: bi[128],bc[128],bo[128],wco[128],fcb[64] (first 4 h-permuted)

__device__ __forceinline__ short f2bf(float f) {
  unsigned u = __float_as_uint(f);
  u += 0x7FFFu + ((u >> 16) & 1u);   // RNE
  return (short)(u >> 16);
}
__device__ __forceinline__ float fexp2(float z) { return __builtin_amdgcn_exp2f(z); }
__device__ __forceinline__ float frcp(float z)  { return __builtin_amdgcn_rcpf(z); }
__device__ __forceinline__ float fsigmoid(float z) {
  return frcp(1.0f + fexp2(-1.44269504f * z));
}
__device__ __forceinline__ float ftanh(float z) {
  return 1.0f - 2.0f * frcp(1.0f + fexp2(2.88539008f * z));
}
// permuted global hid for GEMM1 tile g (0..7), D-row d (0..15)
__device__ __forceinline__ int hperm(int g, int d) {
  return 32 * (g >> 1) + 2 * (g & 1) + 8 * (d >> 2) + 4 * ((d >> 1) & 1) + (d & 1);
}

// ---- repack: weights -> bf16 MFMA A-fragments, biases -> combined fp32 ----
__global__ void repack_kernel(const float* __restrict__ W_i, const float* __restrict__ W_c,
                              const float* __restrict__ W_o, const float* __restrict__ fc_W,
                              const float* __restrict__ bg_i, const float* __restrict__ bg_c,
                              const float* __restrict__ bg_o,
                              const float* __restrict__ b_i, const float* __restrict__ b_c,
                              const float* __restrict__ b_o, const float* __restrict__ wc_o,
                              const float* __restrict__ fc_b,
                              short* __restrict__ wfrag, short* __restrict__ fcfrag,
                              float* __restrict__ bias) {
  int tid = blockIdx.x * blockDim.x + threadIdx.x;
  const int total1 = WFRAG_ELEMS;
  const int total2 = FCFRAG_ELEMS;
  for (int e = tid; e < total1 + total2 + HID + OUT_DIM; e += gridDim.x * blockDim.x) {
    if (e < total1) {
      // A-frag of GEMM1: A row (=D row) cidx of tile g, k=32s+8q+j, PERMUTED h
      int j = e & 7, lane = (e >> 3) & 63, s = (e >> 9) & 1, t = e >> 10;
      int q = lane >> 4, cidx = lane & 15;
      int gate = t >> 3;                       // 0:W_i 1:W_c 2:W_o
      int g = t & 7;
      int h = hperm(g, cidx);
      int feat = 32 * s + 8 * q + j;
      const float* W = (gate == 0) ? W_i : ((gate == 1) ? W_c : W_o);
      wfrag[e] = f2bf(W[feat * HID + h]);
    } else if (e < total1 + total2) {
      // A-frag of GEMM2: A = fc_W^T (64x128), STANDARD hid = 32s+8q+j
      int e2 = e - total1;
      int j = e2 & 7, lane = (e2 >> 3) & 63, s = (e2 >> 9) & 3, t = e2 >> 11;
      int q = lane >> 4, cidx = lane & 15;
      int od = 16 * t + cidx;
      int hid = 32 * s + 8 * q + j;
      fcfrag[e2] = f2bf(fc_W[hid * OUT_DIM + od]);
    } else if (e < total1 + total2 + HID) {
      int p = e - total1 - total2;             // permuted storage index g*16+d
      int h = hperm(p >> 4, p & 15);
      bias[p]           = bg_i[h] + b_i[h];
      bias[HID + p]     = bg_c[h] + b_c[h];
      bias[2 * HID + p] = bg_o[h] + b_o[h];
      bias[3 * HID + p] = wc_o[h];
    } else {
      int h2 = e - total1 - total2 - HID;
      bias[4 * HID + h2] = fc_b[h2];
    }
  }
}

// ---- fused main kernel: 32 rows/wave, no LDS, no barriers, no shuffles ----
__global__ __launch_bounds__(256, 4) void gclstm_fused(
    const float* __restrict__ x, const short* __restrict__ wfrag,
    const short* __restrict__ fcfrag, const float* __restrict__ bias,
    float* __restrict__ out) {
  const int lane = threadIdx.x & 63;
  const int wid = (blockIdx.x * blockDim.x + threadIdx.x) >> 6;
  const int row0 = wid * 32;
  if (row0 >= N_ROWS) return;            // N_ROWS % 32 == 0, full tiles only
  const int q = lane >> 4, c = lane & 15;
  const short* wf = wfrag  + lane * 8;
  const short* ff = fcfrag + lane * 8;

  // x B-fragments: B = x^T; lane supplies col (row row0+16m+c), k=32sk+8q+j
  short8 bx[2][2];
#pragma unroll
  for (int m = 0; m < 2; ++m) {
    const float* xr = x + (size_t)(row0 + 16 * m + c) * IN_DIM + 8 * q;
#pragma unroll
    for (int sk = 0; sk < 2; ++sk) {
      f32x4 f0 = *(const f32x4*)(xr + 32 * sk);
      f32x4 f1 = *(const f32x4*)(xr + 32 * sk + 4);
      short8 v;
      v[0] = f2bf(f0[0]); v[1] = f2bf(f0[1]); v[2] = f2bf(f0[2]); v[3] = f2bf(f0[3]);
      v[4] = f2bf(f1[0]); v[5] = f2bf(f1[1]); v[6] = f2bf(f1[2]); v[7] = f2bf(f1[3]);
      bx[m][sk] = v;
    }
  }

  const float* Bi  = bias;               // permuted (index g*16+d)
  const float* Bc  = bias + HID;
  const float* Bo  = bias + 2 * HID;
  const float* Wco = bias + 3 * HID;
  const float* Fcb = bias + 4 * HID;     // standard od order

  // oacc init = fc bias (folded): lane holds out^T[od=16t+4q+r][xrow=16m+c]
  f32x4 oacc[4][2];
#pragma unroll
  for (int t = 0; t < 4; ++t) {
    f32x4 fb = *(const f32x4*)(Fcb + 16 * t + 4 * q);
    oacc[t][0] = fb; oacc[t][1] = fb;
  }

  union U { unsigned u[4]; short8 s8; };

#pragma unroll
  for (int s = 0; s < 4; ++s) {          // 32-hid block = GEMM2 k-step
    unsigned pk[2][2][2];                // [gg][m][word] bf16x2 gate outputs
#pragma unroll
    for (int gg = 0; gg < 2; ++gg) {
      const int g = 2 * s + gg;
      const int p0 = g * 16 + 4 * q;     // permuted bias index base
      f32x4 vbi = *(const f32x4*)(Bi + p0);
      f32x4 vbc = *(const f32x4*)(Bc + p0);
      f32x4 vbo = *(const f32x4*)(Bo + p0);
      f32x4 vwc = *(const f32x4*)(Wco + p0);
      f32x4 acc[3][2];
#pragma unroll
      for (int m = 0; m < 2; ++m) { acc[0][m] = vbi; acc[1][m] = vbc; acc[2][m] = vbo; }
#pragma unroll
      for (int sk = 0; sk < 2; ++sk) {
        short8 ai = *(const short8*)(wf + ((g     ) * 2 + sk) * 512);
        short8 ac = *(const short8*)(wf + ((g +  8) * 2 + sk) * 512);
        short8 ao = *(const short8*)(wf + ((g + 16) * 2 + sk) * 512);
#pragma unroll
        for (int m = 0; m < 2; ++m) {
          acc[0][m] = __builtin_amdgcn_mfma_f32_16x16x32_bf16(ai, bx[m][sk], acc[0][m], 0, 0, 0);
          acc[1][m] = __builtin_amdgcn_mfma_f32_16x16x32_bf16(ac, bx[m][sk], acc[1][m], 0, 0, 0);
          acc[2][m] = __builtin_amdgcn_mfma_f32_16x16x32_bf16(ao, bx[m][sk], acc[2][m], 0, 0, 0);
        }
      }
      // gates -> bf16 pairs. Lane's D-row d=4q+r maps to hid 32s+2gg+8q+4(r>>1)+(r&1):
      // word0 = (r0,r1) = hids (8q+2gg+0, +1); word1 = (r2,r3) = (8q+2gg+4, +5)
#pragma unroll
      for (int m = 0; m < 2; ++m) {
        short hw[4];
#pragma unroll
        for (int r = 0; r < 4; ++r) {
          float gi = fsigmoid(acc[0][m][r]);
          float gt = ftanh(acc[1][m][r]);
          float C  = gi * gt;
          float go = fsigmoid(acc[2][m][r] + vwc[r] * C);
          hw[r] = f2bf(go * ftanh(C));
        }
        pk[gg][m][0] = (unsigned)(unsigned short)hw[0] | ((unsigned)(unsigned short)hw[1] << 16);
        pk[gg][m][1] = (unsigned)(unsigned short)hw[2] | ((unsigned)(unsigned short)hw[3] << 16);
      }
    }
    // GEMM2 B-frag is this lane's own words: {pk0.w0, pk1.w0, pk0.w1, pk1.w1}
    // (element j <-> hid 32s+8q+j, matching fcfrag's standard k order)
#pragma unroll
    for (int m = 0; m < 2; ++m) {
      U bu;
      bu.u[0] = pk[0][m][0];
      bu.u[1] = pk[1][m][0];
      bu.u[2] = pk[0][m][1];
      bu.u[3] = pk[1][m][1];
#pragma unroll
      for (int t = 0; t < 4; ++t) {
        short8 af = *(const short8*)(ff + (t * 4 + s) * 512);
        oacc[t][m] = __builtin_amdgcn_mfma_f32_16x16x32_bf16(af, bu.s8, oacc[t][m], 0, 0, 0);
      }
    }
  }

  // epilogue: coalesced float4 stores (fc bias already folded)
#pragma unroll
  for (int t = 0; t < 4; ++t) {
    const int od0 = 16 * t + 4 * q;
#pragma unroll
    for (int m = 0; m < 2; ++m) {
      *(f32x4*)(out + (size_t)(row0 + 16 * m + c) * OUT_DIM + od0) = oacc[t][m];
    }
  }
}

extern "C" void kernel_launch(void* const* d_in, const int* in_sizes, int n_in,
                              void* d_out, int out_size, void* d_ws, size_t ws_size,
                              hipStream_t stream) {
  (void)in_sizes; (void)n_in; (void)out_size; (void)ws_size;
  const float* x    = (const float*)d_in[0];
  const float* W_i  = (const float*)d_in[3];
  const float* W_c  = (const float*)d_in[5];
  const float* W_o  = (const float*)d_in[6];
  const float* bg_i = (const float*)d_in[11];
  const float* bg_c = (const float*)d_in[13];
  const float* bg_o = (const float*)d_in[14];
  const float* wc_o = (const float*)d_in[17];
  const float* b_i  = (const float*)d_in[18];
  const float* b_c  = (const float*)d_in[20];
  const float* b_o  = (const float*)d_in[21];
  const float* fc_W = (const float*)d_in[22];
  const float* fc_b = (const float*)d_in[23];

  short* wfrag  = (short*)d_ws;
  short* fcfrag = (short*)((char*)d_ws + FCFRAG_OFF);
  float* bias   = (float*)((char*)d_ws + BIAS_OFF);

  repack_kernel<<<dim3(64), dim3(256), 0, stream>>>(
      W_i, W_c, W_o, fc_W, bg_i, bg_c, bg_o, b_i, b_c, b_o, wc_o, fc_b,
      wfrag, fcfrag, bias);

  const int nwaves = N_ROWS / 32;           // 6250
  const int nwg = (nwaves + 3) / 4;         // 1563 (256-thread WGs, 4 waves)
  gclstm_fused<<<dim3(nwg), dim3(256), 0, stream>>>(
      x, wfrag, fcfrag, bias, (float*)d_out);
}